// Round 8
// baseline (116.476 us; speedup 1.0000x reference)
//
#include <hip/hip_runtime.h>

#define GQ    8192           // bs(32) * Gn(256)
#define C14   1.11803398874989485f   // sqrt(5)/2: 1/T=5 and 1/4 quad-duplication

// DPP quad_perm adds (VALU pipe): 0xB1 = lanes [1,0,3,2] (xor1), 0x4E = [2,3,0,1] (xor2)
template<int CTRL>
__device__ __forceinline__ float dpp_add(float v) {
    int t = __builtin_amdgcn_update_dpp(0, __float_as_int(v), CTRL, 0xF, 0xF, true);
    return v + __int_as_float(t);
}

// ONE WAVE = ONE GROUP. Zero barriers, zero cross-wave exchange, branchless core.
// lane l -> channel (l>>2)+16k (k=round 0..7), samples 4(l&3)..4(l&3)+3 (float4).
// Bucket codes unpacked per-lane from ballot bitmasks (no readlane/switch).
// Quad allreduce per bucket via DPP quad_perm (VALU). Gram partials in regs;
// one final 64-lane reduce-scatter (R7's verified chain) + lane-parallel LSE.
__global__ __launch_bounds__(64, 4) void group_loss_kernel(
    const int*   __restrict__ labs,   // [G*16]
    const float* __restrict__ feats,  // [32,128,256,16]
    const int*   __restrict__ idxs,   // [G*16]
    const float* __restrict__ ctx,    // [128]
    float2*      __restrict__ ws)     // [G] {gl*gv, gv}
{
    __shared__ float SIM[72];                   // per-block (1 wave) scratch

    const int l   = threadIdx.x;
    const int blk = blockIdx.x;
    const int g   = ((blk & 7) << 10) | (blk >> 3);   // XCD-contiguous groups
    const int b   = g >> 8;
    const int gn  = g & 255;
    const long fbase = (long)b * 524288 + (long)gn * 16;
    const int ch0   = l >> 2;                   // channel within round
    const int sbase = (l & 3) * 4;              // first of my 4 samples

    // ---- label/index logic: lanes 0..15 hold sample s=l --------------------
    int myidx = -1, mylab = -2;
    if (l < 16) { myidx = idxs[g * 16 + l]; mylab = labs[g * 16 + l]; }

    // u = count of distinct seed indices (6-bit match-any via ballots)
    unsigned long long mm = ~0ull;
    #pragma unroll
    for (int bit = 0; bit < 6; ++bit) {
        const unsigned long long bb = __ballot((myidx >> bit) & 1);
        mm &= ((myidx >> bit) & 1) ? bb : ~bb;
    }
    const bool dup = (mm & ((1ull << l) - 1) & 0xFFFFull) != 0ull;
    const int u = __popcll(__ballot((l < 16) && !dup));

    const bool valid = l < u;                   // u<=16
    const int bid = valid ? (mylab + 1) : 15;   // 0=bg, 1..8=fg, 15=invalid (4b)

    int cnt9[9];
    #pragma unroll
    for (int r = 0; r < 9; ++r) cnt9[r] = __popcll(__ballot(bid == r));
    const bool has_bg = cnt9[0] > 0;
    int fg_count = 0, pm = 0;
    #pragma unroll
    for (int r = 1; r < 9; ++r)
        if (cnt9[r] > 0) { ++fg_count; pm |= 1 << r; }

    // ---- pack bucket ids into 4 ballot masks; unpack my 4 sample codes -----
    unsigned bm[4];
    #pragma unroll
    for (int bit = 0; bit < 4; ++bit)
        bm[bit] = (unsigned)__ballot((bid >> bit) & 1);
    int code[4];
    #pragma unroll
    for (int k = 0; k < 4; ++k) {
        const int s = sbase + k;
        code[k] = ((bm[0] >> s) & 1) | (((bm[1] >> s) & 1) << 1)
                | (((bm[2] >> s) & 1) << 2) | (((bm[3] >> s) & 1) << 3);
    }

    // ---- per-bucket scale (sqrt5/2 carries 1/T and quad-dup correction) ----
    float sc[9];
    #pragma unroll
    for (int r = 0; r < 9; ++r)
        sc[r] = C14 / (float)(cnt9[r] > 0 ? cnt9[r] : 1);
    float ctxv[8];
    #pragma unroll
    for (int k = 0; k < 8; ++k) ctxv[k] = ctx[ch0 + 16 * k];

    // ---- 8 rounds: load float4, bucket-accumulate (branchless), quad-reduce,
    //      scale, accumulate 44 Gram partials in registers --------------------
    const int PI_[44] = {1,1, 2,2,2, 3,3,3,3, 4,4,4,4,4, 5,5,5,5,5,5,
                         6,6,6,6,6,6,6, 7,7,7,7,7,7,7,7, 8,8,8,8,8,8,8,8,8};
    const int PJ_[44] = {0,1, 0,1,2, 0,1,2,3, 0,1,2,3,4, 0,1,2,3,4,5,
                         0,1,2,3,4,5,6, 0,1,2,3,4,5,6,7, 0,1,2,3,4,5,6,7,8};
    float simp[44];
    #pragma unroll
    for (int k = 0; k < 44; ++k) simp[k] = 0.0f;

    #pragma unroll
    for (int k = 0; k < 8; ++k) {
        const float4 v = *(const float4*)(feats + fbase
                            + (long)(ch0 + 16 * k) * 4096 + sbase);
        float acc[9];
        #pragma unroll
        for (int r = 0; r < 9; ++r) acc[r] = 0.0f;
        #pragma unroll
        for (int e = 0; e < 4; ++e) {
            const float x = (e == 0) ? v.x : (e == 1) ? v.y : (e == 2) ? v.z : v.w;
            const int  c = code[e];
            #pragma unroll
            for (int r = 0; r < 9; ++r)
                acc[r] += (c == r) ? x : 0.0f;           // cndmask-add, no branch
        }
        float m[9];
        #pragma unroll
        for (int r = 0; r < 9; ++r) {                     // quad allreduce (VALU)
            float t = dpp_add<0xB1>(acc[r]);
            t = dpp_add<0x4E>(t);
            m[r] = t * sc[r];
        }
        m[0] = has_bg ? m[0] : ctxv[k] * C14;             // bg row = context
        #pragma unroll
        for (int p = 0; p < 44; ++p)
            simp[p] += m[PI_[p]] * m[PJ_[p]];
    }

    // ---- final reduce over 64 lanes: rows 1..8 reduce-scattered ------------
    const int OFF_[9] = {0, 0, 2, 5, 9, 14, 20, 27, 35};
    #pragma unroll
    for (int r = 1; r <= 8; ++r) {
        float p[8];
        #pragma unroll
        for (int j = 0; j < 8; ++j) {
            const int idx = (j <= r) ? (OFF_[r] + j) : (OFF_[j] + r);
            p[j] = simp[idx];
        }
        #pragma unroll
        for (int i = 0; i < 4; ++i) {            // d=32 scatter
            const float send = (l & 32) ? p[i] : p[i + 4];
            const float recv = __shfl_xor(send, 32);
            p[i] = ((l & 32) ? p[i + 4] : p[i]) + recv;
        }
        #pragma unroll
        for (int i = 0; i < 2; ++i) {            // d=16 scatter
            const float send = (l & 16) ? p[i] : p[i + 2];
            const float recv = __shfl_xor(send, 16);
            p[i] = ((l & 16) ? p[i + 2] : p[i]) + recv;
        }
        {                                        // d=8 scatter
            const float send = (l & 8) ? p[0] : p[1];
            const float recv = __shfl_xor(send, 8);
            p[0] = ((l & 8) ? p[1] : p[0]) + recv;
        }
        p[0] += __shfl_xor(p[0], 4);
        p[0] = dpp_add<0x4E>(p[0]);              // d=2 (VALU)
        p[0] = dpp_add<0xB1>(p[0]);              // d=1 (VALU)
        if ((l & 7) == 0) SIM[(r - 1) * 8 + (l >> 3)] = p[0];
    }
    // sim(8,8): full butterfly, all lanes hold total
    float s88 = simp[43];
    s88 += __shfl_xor(s88, 1);  s88 += __shfl_xor(s88, 2);
    s88 += __shfl_xor(s88, 4);  s88 += __shfl_xor(s88, 8);
    s88 += __shfl_xor(s88, 16); s88 += __shfl_xor(s88, 32);

    __syncthreads();                             // 1-wave block: lgkmcnt drain

    // ---- lane-parallel masked LSE: lane r = row r (1..8) -------------------
    const int cm = pm | 1;                       // col 0 (bg/ctx) always valid
    const float NINF = __int_as_float(0xFF800000);
    float li = 0.0f;
    if (l >= 1 && l <= 8) {
        const float* Rw = SIM + (l - 1) * 8;
        const float4 ra = *(const float4*)(Rw);
        const float4 rb = *(const float4*)(Rw + 4);
        const float s8 = SIM[56 + l];            // junk for l==8 (in-range)
        float srow[9] = { ra.x, ra.y, ra.z, ra.w, rb.x, rb.y, rb.z, rb.w,
                          (l == 8) ? s88 : s8 };
        float vmax = NINF, diag = 0.0f, vv[9];
        #pragma unroll
        for (int j = 0; j < 9; ++j) {
            vv[j] = ((cm >> j) & 1) ? srow[j] : NINF;
            vmax = fmaxf(vmax, vv[j]);
            if (j >= 1) diag = (l == j) ? srow[j] : diag;
        }
        float se = 0.0f;
        #pragma unroll
        for (int j = 0; j < 9; ++j) se += __expf(vv[j] - vmax);  // exp(-inf)=0
        li = vmax + __logf(se) - diag;
        li = ((pm >> l) & 1) ? li : 0.0f;        // absent row contributes 0
    }

    // ---- sum li over lanes 1..8 -> lane 0; single float2 store -------------
    float ssum = li;
    ssum += __shfl_down(ssum, 8);
    ssum += __shfl_down(ssum, 4);
    ssum += __shfl_down(ssum, 2);
    ssum += __shfl_down(ssum, 1);
    if (l == 0) {
        float2 r;
        r.x = ssum / (float)(fg_count > 0 ? fg_count : 1);  // gl*gv
        r.y = (fg_count > 0) ? 1.0f : 0.0f;                 // gv
        ws[g] = r;
    }
}

// Deterministic 8192 -> 1 reduction
__global__ __launch_bounds__(1024) void reduce_kernel(
    const float2* __restrict__ ws, float* __restrict__ out)
{
    __shared__ float sa[1024], sb[1024];
    const int t = threadIdx.x;
    float a = 0.0f, b2 = 0.0f;
    #pragma unroll
    for (int i = 0; i < GQ / 1024; ++i) {
        const float2 v = ws[t + i * 1024];
        a += v.x; b2 += v.y;
    }
    sa[t] = a; sb[t] = b2;
    __syncthreads();
    for (int off = 512; off > 0; off >>= 1) {
        if (t < off) { sa[t] += sa[t + off]; sb[t] += sb[t + off]; }
        __syncthreads();
    }
    if (t == 0) out[0] = 0.1f * (sa[0] / sb[0]);
}

extern "C" void kernel_launch(void* const* d_in, const int* in_sizes, int n_in,
                              void* d_out, int out_size, void* d_ws, size_t ws_size,
                              hipStream_t stream) {
    const int*   labs  = (const int*)d_in[0];    // proposal_instance_mask
    const float* feats = (const float*)d_in[1];  // grouped_features
    const int*   idxs  = (const int*)d_in[2];    // grouped_indices
    const float* ctx   = (const float*)d_in[3];  // context_compen
    float* out = (float*)d_out;
    float2* ws = (float2*)d_ws;

    group_loss_kernel<<<GQ, 64, 0, stream>>>(labs, feats, idxs, ctx, ws);
    reduce_kernel<<<1, 1024, 0, stream>>>(ws, out);
}